// Round 1
// baseline (617.768 us; speedup 1.0000x reference)
//
#include <hip/hip_runtime.h>
#include <cmath>

#ifndef M_PI
#define M_PI 3.14159265358979323846
#endif

static constexpr int HH = 2048;
static constexpr int WW = 2048;

struct Offs { int v[49]; int maxo; };

// out = filt(t) / N   (mean over valid slanted-line taps)
__global__ __launch_bounds__(256) void filt_div(const float* __restrict__ t,
                                                float* __restrict__ out, Offs o) {
  const int w = blockIdx.x * 64 + threadIdx.x;
  const int h = blockIdx.y * 4 + threadIdx.y;
  float sum = 0.0f;
  if (h >= 24 && h < HH - 24 && w >= o.maxo && w < WW - o.maxo) {
#pragma unroll
    for (int d = -24; d <= 24; ++d) {
      sum += t[(h + d) * WW + (w + o.v[d + 24])];
    }
    out[h * WW + w] = sum * (1.0f / 49.0f);
  } else {
    int cnt = 0;
#pragma unroll
    for (int d = -24; d <= 24; ++d) {
      const int hh = h + d, ww = w + o.v[d + 24];
      if (hh >= 0 && hh < HH && ww >= 0 && ww < WW) {
        sum += t[hh * WW + ww];
        ++cnt;
      }
    }
    out[h * WW + w] = sum / (float)cnt;
  }
}

// res = xc[i] + filt(b)/N ; xcout[i] = res - (Xsub ? Xsub[i] : 0) ; tout[i] = y[i] - res (if tout)
__global__ __launch_bounds__(256) void filt_acc(const float* __restrict__ b,
                                                const float* xc, float* xcout,
                                                const float* __restrict__ Xsub,
                                                const float* __restrict__ y,
                                                float* __restrict__ tout, Offs o) {
  const int w = blockIdx.x * 64 + threadIdx.x;
  const int h = blockIdx.y * 4 + threadIdx.y;
  const int i = h * WW + w;
  float sum = 0.0f;
  float res;
  if (h >= 24 && h < HH - 24 && w >= o.maxo && w < WW - o.maxo) {
#pragma unroll
    for (int d = -24; d <= 24; ++d) {
      sum += b[(h + d) * WW + (w + o.v[d + 24])];
    }
    res = xc[i] + sum * (1.0f / 49.0f);
  } else {
    int cnt = 0;
#pragma unroll
    for (int d = -24; d <= 24; ++d) {
      const int hh = h + d, ww = w + o.v[d + 24];
      if (hh >= 0 && hh < HH && ww >= 0 && ww < WW) {
        sum += b[hh * WW + ww];
        ++cnt;
      }
    }
    res = xc[i] + sum / (float)cnt;
  }
  if (tout) tout[i] = y[i] - res;
  xcout[i] = Xsub ? (res - Xsub[i]) : res;
}

__global__ __launch_bounds__(256) void sub_k(const float* __restrict__ a,
                                             const float* __restrict__ c,
                                             float* __restrict__ o, int n) {
  const int i = blockIdx.x * 256 + threadIdx.x;
  if (i < n) o[i] = a[i] - c[i];
}

__device__ __forceinline__ float reflectf(float x, int size) {
  const float span = (float)(size - 1);
  const float ax = fabsf(x);
  const float extra = fmodf(ax, span);
  const float flips = floorf(ax / span);
  float r = (fmodf(flips, 2.0f) == 0.0f) ? extra : (span - extra);
  return fminf(fmaxf(r, 0.0f), span);
}

__global__ __launch_bounds__(256) void gather_k(const float* __restrict__ D,
                                                const float* __restrict__ coor,
                                                const float* __restrict__ hX,
                                                float* __restrict__ out) {
  const int i = blockIdx.x * 256 + threadIdx.x;
  const float cx = coor[2 * i + 0];
  const float cy = coor[2 * i + 1];
  const float gx = reflectf((cx + 1.0f) * 0.5f * (float)(WW - 1), WW);
  const float gy = reflectf((cy + 1.0f) * 0.5f * (float)(HH - 1), HH);
  const float x0 = floorf(gx), y0 = floorf(gy);
  const float wx = gx - x0, wy = gy - y0;
  int xi0 = (int)x0;         xi0 = min(max(xi0, 0), WW - 1);
  int yi0 = (int)y0;         yi0 = min(max(yi0, 0), HH - 1);
  int xi1 = (int)(x0 + 1.0f); xi1 = min(max(xi1, 0), WW - 1);
  int yi1 = (int)(y0 + 1.0f); yi1 = min(max(yi1, 0), HH - 1);
  const float v00 = D[yi0 * WW + xi0];
  const float v01 = D[yi0 * WW + xi1];
  const float v10 = D[yi1 * WW + xi0];
  const float v11 = D[yi1 * WW + xi1];
  out[i] = v00 * (1.0f - wx) * (1.0f - wy) + v01 * wx * (1.0f - wy) +
           v10 * (1.0f - wx) * wy + v11 * wx * wy + hX[i];
}

extern "C" void kernel_launch(void* const* d_in, const int* in_sizes, int n_in,
                              void* d_out, int out_size, void* d_ws, size_t ws_size,
                              hipStream_t stream) {
  const float* X    = (const float*)d_in[0];
  const float* y    = (const float*)d_in[1];
  const float* hX   = (const float*)d_in[2];
  const float* coor = (const float*)d_in[3];
  float* out = (float*)d_out;

  float* Xc = (float*)d_ws;                       // H*W floats
  float* t  = (float*)d_ws + (size_t)HH * WW;     // H*W floats
  float* b  = out;                                // reuse d_out as filter scratch

  static const double angles[3] = {-10.0, 0.0, 10.0};
  Offs offs[3];
  for (int a = 0; a < 3; ++a) {
    const double ta = tan(angles[a] * M_PI / 180.0);
    int mx = 0;
    for (int j = 0; j < 49; ++j) {
      const int r = (int)lrint((double)(j - 24) * ta);  // round-half-even, matches np.round
      offs[a].v[j] = r;
      const int ar = r < 0 ? -r : r;
      if (ar > mx) mx = ar;
    }
    offs[a].maxo = mx;
  }

  const int n = HH * WW;
  dim3 blk(64, 4, 1), grd(WW / 64, HH / 4, 1);

  sub_k<<<n / 256, 256, 0, stream>>>(y, X, t, n);
  // iteration 0 (Xc = X)
  filt_div<<<grd, blk, 0, stream>>>(t, b, offs[0]);
  filt_acc<<<grd, blk, 0, stream>>>(b, X, Xc, nullptr, y, t, offs[0]);
  // iteration 1
  filt_div<<<grd, blk, 0, stream>>>(t, b, offs[1]);
  filt_acc<<<grd, blk, 0, stream>>>(b, Xc, Xc, nullptr, y, t, offs[1]);
  // iteration 2 (write D = Xc - X directly)
  filt_div<<<grd, blk, 0, stream>>>(t, b, offs[2]);
  filt_acc<<<grd, blk, 0, stream>>>(b, Xc, Xc, X, y, nullptr, offs[2]);
  // grid_sample(D, coor) + hX
  gather_k<<<n / 256, 256, 0, stream>>>(Xc, coor, hX, out);
}

// Round 2
// 231.414 us; speedup vs baseline: 2.6695x; 2.6695x over previous
//
#include <hip/hip_runtime.h>
#include <hip/hip_fp16.h>

static constexpr int HH = 2048;
static constexpr int WW = 2048;
static constexpr int PADT = 24;   // top pad rows (also bottom)
static constexpr int PADL = 8;    // left pad cols (also right; need 4, use 8 for alignment)
static constexpr int SW   = WW + 2 * PADL;          // 2064 floats, row stride of padded bufs
static constexpr int PROWS = HH + 2 * PADT;         // 2096 rows
static constexpr size_t PadElems = (size_t)PROWS * SW;  // 4,326,144

// segment tables for +10 deg: lval(d)=round(d*tan(10deg)), runs of constant offset
// (s,e) = d-range, o = column offset.  -10 deg: negate o.
__device__ constexpr int CS[9] = {-24,-19,-14,-8,-2, 3, 9,15,20};
__device__ constexpr int CE[9] = {-20,-15, -9,-3, 2, 8,14,19,24};
__device__ constexpr int CO[9] = { -4, -3, -2,-1, 0, 1, 2, 3, 4};

// ---- one slanted segment: vertical run [SS,EE] at col offset OO, 16 output rows ----
template<int SS, int EE, int OO>
__device__ __forceinline__ void seg_one(const float* __restrict__ tp, int h0, int w,
                                        float* __restrict__ acc) {
  constexpr int L = EE - SS + 1;        // 5 or 6
  const float* p = tp + (h0 + SS + PADT) * SW + (w + OO + PADL);
  float ring[L - 1];
  float s = 0.0f;
#pragma unroll
  for (int k = 0; k < L - 1; ++k) { float v = p[k * SW]; ring[k] = v; s += v; }
#pragma unroll
  for (int r = 0; r < 16; ++r) {
    float v = p[(L - 1 + r) * SW];      // row h0+EE+r
    acc[r] += s + v;
    s += v - ring[r % (L - 1)];
    ring[r % (L - 1)] = v;
  }
}

template<int SGN>   // +1 => +10deg, -1 => -10deg
__device__ __forceinline__ void filt_slant(const float* __restrict__ tp, int h0, int w,
                                           float* __restrict__ acc) {
  seg_one<-24, -20, -4 * SGN>(tp, h0, w, acc);
  seg_one<-19, -15, -3 * SGN>(tp, h0, w, acc);
  seg_one<-14,  -9, -2 * SGN>(tp, h0, w, acc);
  seg_one< -8,  -3, -1 * SGN>(tp, h0, w, acc);
  seg_one< -2,   2,  0      >(tp, h0, w, acc);
  seg_one<  3,   8,  1 * SGN>(tp, h0, w, acc);
  seg_one<  9,  14,  2 * SGN>(tp, h0, w, acc);
  seg_one< 15,  19,  3 * SGN>(tp, h0, w, acc);
  seg_one< 20,  24,  4 * SGN>(tp, h0, w, acc);
}

// A: 0 => -10deg, 1 => 0deg, 2 => +10deg
template<int A>
__device__ __forceinline__ void filt16(const float* __restrict__ tp, int h0, int w,
                                       float* __restrict__ acc) {
#pragma unroll
  for (int r = 0; r < 16; ++r) acc[r] = 0.0f;
  if constexpr (A == 1) {
    // single 49-row vertical segment, sliding window with re-load of leaving element
    const float* p = tp + (h0 - 24 + PADT) * SW + (w + PADL);
    float s = 0.0f;
#pragma unroll
    for (int k = 0; k < 48; ++k) s += p[k * SW];        // rows h0-24 .. h0+23
#pragma unroll
    for (int r = 0; r < 16; ++r) {
      float vin = p[(48 + r) * SW];                     // row h0+24+r
      acc[r] = s + vin;
      s += vin - p[r * SW];                             // drop row h0-24+r
    }
  } else if constexpr (A == 0) {
    filt_slant<-1>(tp, h0, w, acc);
  } else {
    filt_slant<+1>(tp, h0, w, acc);
  }
}

// analytic 1/N (N = in-bounds tap count, zero-padded conv of ones)
template<int A>
__device__ __forceinline__ float rcpcnt(int h, int w) {
  if (h >= 24 && h <= 2023 && w >= 4 && w <= 2043) return 1.0f / 49.0f;
  int cnt = 0;
  if constexpr (A == 1) {
    cnt = min(h + 24, HH - 1) - max(h - 24, 0) + 1;
  } else {
    const int sgn = (A == 0) ? -1 : 1;
#pragma unroll
    for (int j = 0; j < 9; ++j) {
      const int ww = w + sgn * CO[j];
      const int ov = min(h + CE[j], HH - 1) - max(h + CS[j], 0) + 1;
      if (ww >= 0 && ww < WW && ov > 0) cnt += ov;
    }
  }
  return 1.0f / (float)cnt;
}

// ---- pass A: bp = filt(tp)/N ----
template<int A>
__global__ __launch_bounds__(256) void passA(const float* __restrict__ tp,
                                             float* __restrict__ bp) {
  const int w  = blockIdx.x * 256 + threadIdx.x;
  const int h0 = blockIdx.y * 16;
  float acc[16];
  filt16<A>(tp, h0, w, acc);
#pragma unroll
  for (int r = 0; r < 16; ++r) {
    const int h = h0 + r;
    bp[(h + PADT) * SW + (w + PADL)] = acc[r] * rcpcnt<A>(h, w);
  }
}

// ---- pass B: res = xcin + filt(bp)/N; then either {xcout=res, tp=y-res} or {dh=half(res-X)} ----
template<int A, bool FINAL>
__global__ __launch_bounds__(256) void passB(const float* __restrict__ bp,
                                             const float* __restrict__ xcin,
                                             const float* __restrict__ aux,   // y (mid) or X (final)
                                             float* __restrict__ xcout,
                                             float* __restrict__ tp,
                                             __half* __restrict__ dh) {
  const int w  = blockIdx.x * 256 + threadIdx.x;
  const int h0 = blockIdx.y * 16;
  float acc[16];
  filt16<A>(bp, h0, w, acc);
#pragma unroll
  for (int r = 0; r < 16; ++r) {
    const int h = h0 + r;
    const size_t i = (size_t)h * WW + w;
    const float res = xcin[i] + acc[r] * rcpcnt<A>(h, w);
    if constexpr (FINAL) {
      dh[i] = __float2half(res - aux[i]);          // aux = X
    } else {
      xcout[i] = res;
      tp[(h + PADT) * SW + (w + PADL)] = aux[i] - res;  // aux = y
    }
  }
}

// zero the pad frame of both staging buffers
__global__ __launch_bounds__(64) void zeropad(float* __restrict__ tp, float* __restrict__ bp) {
  float* buf = blockIdx.y ? bp : tp;
  const int row = blockIdx.x;
  float* r = buf + (size_t)row * SW;
  if (row < PADT || row >= PADT + HH) {
    for (int c = threadIdx.x; c < SW; c += 64) r[c] = 0.0f;
  } else if (threadIdx.x < PADL) {
    r[threadIdx.x] = 0.0f;
    r[PADL + WW + threadIdx.x] = 0.0f;
  }
}

// tp interior = y - X
__global__ __launch_bounds__(256) void sub2pad(const float* __restrict__ y,
                                               const float* __restrict__ X,
                                               float* __restrict__ tp) {
  const int i = blockIdx.x * 256 + threadIdx.x;
  const int h = i >> 11, w = i & (WW - 1);
  tp[(h + PADT) * SW + (w + PADL)] = y[i] - X[i];
}

__device__ __forceinline__ float reflectf(float x, int size) {
  const float span = (float)(size - 1);
  const float ax = fabsf(x);
  const float extra = fmodf(ax, span);
  const float flips = floorf(ax / span);
  float r = (fmodf(flips, 2.0f) == 0.0f) ? extra : (span - extra);
  return fminf(fmaxf(r, 0.0f), span);
}

__global__ __launch_bounds__(256) void gather_k(const __half* __restrict__ D,
                                                const float* __restrict__ coor,
                                                const float* __restrict__ hX,
                                                float* __restrict__ out) {
  const int i = blockIdx.x * 256 + threadIdx.x;
  const float cx = coor[2 * i + 0];
  const float cy = coor[2 * i + 1];
  const float gx = reflectf((cx + 1.0f) * 0.5f * (float)(WW - 1), WW);
  const float gy = reflectf((cy + 1.0f) * 0.5f * (float)(HH - 1), HH);
  const float x0 = floorf(gx), y0 = floorf(gy);
  const float wx = gx - x0, wy = gy - y0;
  int xi0 = (int)x0;          xi0 = min(max(xi0, 0), WW - 1);
  int yi0 = (int)y0;          yi0 = min(max(yi0, 0), HH - 1);
  int xi1 = (int)(x0 + 1.0f); xi1 = min(max(xi1, 0), WW - 1);
  int yi1 = (int)(y0 + 1.0f); yi1 = min(max(yi1, 0), HH - 1);
  const float v00 = __half2float(D[yi0 * WW + xi0]);
  const float v01 = __half2float(D[yi0 * WW + xi1]);
  const float v10 = __half2float(D[yi1 * WW + xi0]);
  const float v11 = __half2float(D[yi1 * WW + xi1]);
  out[i] = v00 * (1.0f - wx) * (1.0f - wy) + v01 * wx * (1.0f - wy) +
           v10 * (1.0f - wx) * wy + v11 * wx * wy + hX[i];
}

extern "C" void kernel_launch(void* const* d_in, const int* in_sizes, int n_in,
                              void* d_out, int out_size, void* d_ws, size_t ws_size,
                              hipStream_t stream) {
  const float* X    = (const float*)d_in[0];
  const float* y    = (const float*)d_in[1];
  const float* hX   = (const float*)d_in[2];
  const float* coor = (const float*)d_in[3];
  float* out = (float*)d_out;

  float*  tp = (float*)d_ws;            // padded t,   17.3 MB
  float*  bp = tp + PadElems;           // padded b,   17.3 MB
  __half* dh = (__half*)(bp + PadElems);// fp16 D,      8.4 MB
  float*  Xc = out;                     // Xc lives in d_out until the final gather rewrites it

  const int n = HH * WW;
  dim3 fgrd(WW / 256, HH / 16, 1);      // (8, 128)

  zeropad<<<dim3(PROWS, 2, 1), 64, 0, stream>>>(tp, bp);
  sub2pad<<<n / 256, 256, 0, stream>>>(y, X, tp);

  // iteration 0: -10deg  (Xc starts as X)
  passA<0><<<fgrd, 256, 0, stream>>>(tp, bp);
  passB<0, false><<<fgrd, 256, 0, stream>>>(bp, X, y, Xc, tp, nullptr);
  // iteration 1: 0deg
  passA<1><<<fgrd, 256, 0, stream>>>(tp, bp);
  passB<1, false><<<fgrd, 256, 0, stream>>>(bp, Xc, y, Xc, tp, nullptr);
  // iteration 2: +10deg  (emit D = Xc - X as fp16)
  passA<2><<<fgrd, 256, 0, stream>>>(tp, bp);
  passB<2, true><<<fgrd, 256, 0, stream>>>(bp, Xc, X, nullptr, nullptr, dh);

  gather_k<<<n / 256, 256, 0, stream>>>(dh, coor, hX, out);
}